// Round 1
// 627.361 us; speedup vs baseline: 1.1373x; 1.1373x over previous
//
#include <hip/hip_runtime.h>
#include <math.h>

// Problem constants (N=80000, Rr=5, A=8, D=32, T=32, K=8 rotations, ROT_DELTA=1)
#define RR 5
#define AA 8
#define DD 32
#define TT 32
#define KK 8

#define RT2 0.70710678118654752f

typedef float v2f __attribute__((ext_vector_type(2)));
typedef float v4f __attribute__((ext_vector_type(4)));

static __device__ __forceinline__ v2f pkfma(v2f a, v2f b, v2f c) {
#if __has_builtin(__builtin_elementwise_fma)
    return __builtin_elementwise_fma(a, b, c);
#else
    v2f r; r.x = fmaf(a.x, b.x, c.x); r.y = fmaf(a.y, b.y, c.y); return r;
#endif
}
static __device__ __forceinline__ v4f pkfma4(v4f a, v4f b, v4f c) {
#if __has_builtin(__builtin_elementwise_fma)
    return __builtin_elementwise_fma(a, b, c);
#else
    v4f r;
    r.x = fmaf(a.x, b.x, c.x); r.y = fmaf(a.y, b.y, c.y);
    r.z = fmaf(a.z, b.z, c.z); r.w = fmaf(a.w, b.w, c.w);
    return r;
#endif
}

// ---------------------------------------------------------------------------
// prep: zero stats workspace + W spectral precompute for BOTH layers.
// New Ws layout: per (r,d) a 256-float row: [half0: t*4 = {F0,F4,R1,I1}]
//                                           [half1: t*4 = {R2,I2,R3,I3}]
//   Ws[(r*32+d)*256 + half*128 + t*4 + k]
// => GEMM-phase W reads have t-stride 4 floats (4 banks): conflict-free, and
// LDS staging stays a straight contiguous copy.
// grid = 40 blocks: 0..19 -> W1, 20..39 -> W2. One thread per (t,r,d).
// ---------------------------------------------------------------------------
__global__ void prep_kernel(const float* __restrict__ W1, const float* __restrict__ W2,
                            float* __restrict__ Ws1, float* __restrict__ Ws2,
                            double* __restrict__ dz, float* __restrict__ fz) {
    int b = blockIdx.x;
    int tid = threadIdx.x;
    if (b == 0 && tid < 128) { dz[tid] = 0.0; fz[tid] = 0.f; }
    int which = (b >= 20) ? 1 : 0;
    const float* __restrict__ W = which ? W2 : W1;
    float* __restrict__ Ws = which ? Ws2 : Ws1;
    int idx = (b - which * 20) * 256 + tid;
    if (idx >= TT * RR * DD) return;
    int d = idx & 31;
    int tr = idx >> 5;      // t*5+r
    int t = tr / 5;
    int r = tr - t * 5;
    float xa[8];
    #pragma unroll
    for (int a = 0; a < 8; ++a) xa[a] = W[(tr * 8 + a) * 32 + d];
    float s0 = xa[0] + xa[4], d0 = xa[0] - xa[4];
    float s1 = xa[1] + xa[5], d1 = xa[1] - xa[5];
    float s2 = xa[2] + xa[6], d2 = xa[2] - xa[6];
    float s3 = xa[3] + xa[7], d3 = xa[3] - xa[7];
    float s02 = s0 + s2, s13 = s1 + s3;
    float F0 = s02 + s13, F4 = s02 - s13;
    float R2 = s0 - s2, I2 = s3 - s1;
    float u = RT2 * (d1 - d3), v = RT2 * (d1 + d3);
    float R1 = d0 + u, R3 = d0 - u;
    float I1 = -d2 - v, I3 = d2 - v;
    float* o = &Ws[(size_t)(r * 32 + d) * 256];
    *(v4f*)&o[t * 4]       = (v4f){F0, F4, R1, I1};
    *(v4f*)&o[128 + t * 4] = (v4f){R2, I2, R3, I3};
}

// ---------------------------------------------------------------------------
// Fused kernel: gather + barycentric interp + forward DFT8 + spectral GEMM
// + IDFT8 + bias + angular max pool + fused per-column stats (sum/sumsq).
//
// Block = 256 threads (4 waves), 64 vertices/block.
// Gather: 8 lanes per vertex (v4f row slices); bc_idx/bc_w loaded as
// int4/float4 (24 contiguous, 16B-aligned values per (v,r)).
// GEMM lane tile = 2 vertices x 4 t; vertex pair is (v, v+8) so the 8
// broadcast Is addresses stride 260 floats == 4 (mod 32) banks ->
// conflict-free; W reads stride 4 floats -> conflict-free.
// Wave wv owns vertices [wv*16, wv*16+16) exclusively -> norm reduction is
// wave-local (shfl over tg bits), stats reduction over vg bits.
// ---------------------------------------------------------------------------
__global__ __launch_bounds__(256, 2)
void fused_conv_kernel(const float* __restrict__ sig,
                       const int* __restrict__ bc_idx,
                       const float* __restrict__ bc_w,
                       const float* __restrict__ Wsg,
                       const float* __restrict__ bias,
                       float* __restrict__ s_out,
                       double* __restrict__ sums,
                       double* __restrict__ sumsq,
                       int N) {
    __shared__ float Is[64 * 260];   // 66560 B spectral interp, stride 260
    __shared__ float Wl[8 * 256];    // 8192 B quarter W slice [d][half][t][4]

    int tid = threadIdx.x;
    int vBase = blockIdx.x * 64;
    int lane = tid & 63;
    int wv = tid >> 6;

    // GEMM lane roles
    int vg = lane & 7;
    int tg = lane >> 3;              // 0..7
    int v0L = wv * 16 + vg;          // pair = (v0L, v0L+8): bank-friendly
    int v1L = v0L + 8;
    int v0 = vBase + v0L;
    int v1 = vBase + v1L;

    // gather-phase lane roles (v4f granularity, 8 lanes per vertex row)
    int d4 = tid & 7;                // floats 4*d4 .. 4*d4+3
    int g = tid >> 3;                // 0..31

    // spectral accumulators per (vv in {0,1}, j in 0..3):
    // A0=(C0,C4) A1=(R1,I1) A2=(R2,I2) A3=(R3,I3)
    v2f A0[2][4], A1[2][4], A2[2][4], A3[2][4];
    #pragma unroll
    for (int vv = 0; vv < 2; ++vv)
        #pragma unroll
        for (int j = 0; j < 4; ++j) {
            A0[vv][j] = (v2f){0.f, 0.f}; A1[vv][j] = (v2f){0.f, 0.f};
            A2[vv][j] = (v2f){0.f, 0.f}; A3[vv][j] = (v2f){0.f, 0.f};
        }

    const v4f* Ws4 = (const v4f*)Wsg;

    for (int r = 0; r < RR; ++r) {
        __syncthreads();  // previous r's GEMM done with Is

        // ---- gather + interp + forward DFT8 -> Is ----
        #pragma unroll
        for (int vv0 = 0; vv0 < 2; ++vv0) {
            int vv = g + vv0 * 32;           // 0..63
            int vgl = vBase + vv;
            int vgc = (vgl < N) ? vgl : (N - 1);
            int base = vgc * 120 + r * 24;   // 16B-aligned (480*v + 96*r bytes)
            int idxv[24]; float wbc[24];
            const int4* ib = (const int4*)(bc_idx + base);
            const float4* fb = (const float4*)(bc_w + base);
            #pragma unroll
            for (int q = 0; q < 6; ++q) {
                *(int4*)&idxv[q * 4] = ib[q];
                *(float4*)&wbc[q * 4] = fb[q];
            }
            v4f xa[8];
            #pragma unroll
            for (int a = 0; a < 8; ++a) {
                int i0 = idxv[a * 3 + 0];
                int i1 = idxv[a * 3 + 1];
                int i2 = idxv[a * 3 + 2];
                v4f r0 = *(const v4f*)&sig[(size_t)i0 * 32 + 4 * d4];
                v4f r1 = *(const v4f*)&sig[(size_t)i1 * 32 + 4 * d4];
                v4f r2 = *(const v4f*)&sig[(size_t)i2 * 32 + 4 * d4];
                float w0 = wbc[a * 3 + 0];
                float w1 = wbc[a * 3 + 1];
                float w2 = wbc[a * 3 + 2];
                v4f w0v = (v4f){w0, w0, w0, w0};
                v4f w1v = (v4f){w1, w1, w1, w1};
                v4f w2v = (v4f){w2, w2, w2, w2};
                xa[a] = pkfma4(w2v, r2, pkfma4(w1v, r1, w0v * r0));
            }
            // DFT8 (4 d-channels packed)
            v4f s0 = xa[0] + xa[4], dd0 = xa[0] - xa[4];
            v4f s1 = xa[1] + xa[5], dd1 = xa[1] - xa[5];
            v4f s2 = xa[2] + xa[6], dd2 = xa[2] - xa[6];
            v4f s3 = xa[3] + xa[7], dd3 = xa[3] - xa[7];
            v4f s02 = s0 + s2, s13 = s1 + s3;
            v4f F0 = s02 + s13, F4 = s02 - s13;
            v4f R2 = s0 - s2, I2 = s3 - s1;
            v4f u = RT2 * (dd1 - dd3), vt = RT2 * (dd1 + dd3);
            v4f R1 = dd0 + u, R3 = dd0 - u;
            v4f I1 = -dd2 - vt, I3 = dd2 - vt;
            // transpose to per-d spectra and write (8 x b128)
            float* ob = &Is[vv * 260 + d4 * 32];
            #pragma unroll
            for (int di = 0; di < 4; ++di) {
                *(v4f*)&ob[di * 8]     = (v4f){F0[di], F4[di], R1[di], I1[di]};
                *(v4f*)&ob[di * 8 + 4] = (v4f){R2[di], I2[di], R3[di], I3[di]};
            }
        }

        // ---- 4 W quarter-stages of 8 d each ----
        for (int ws = 0; ws < 4; ++ws) {
            __syncthreads();  // ws=0: gather visible; ws>0: prev GEMM done with Wl
            {
                // stage Ws[r][ws*8 .. ws*8+8) -> Wl (2048 floats, contiguous)
                const v4f* src = Ws4 + (size_t)(r * 32 + ws * 8) * 64;
                float* dst = &Wl[tid * 8];
                v4f a = src[tid * 2];
                v4f b = src[tid * 2 + 1];
                *(v4f*)dst = a;
                *(v4f*)(dst + 4) = b;
            }
            __syncthreads();  // Wl visible

            #pragma unroll 2
            for (int dl = 0; dl < 8; ++dl) {
                const float* ip = &Is[v0L * 260 + (ws * 8 + dl) * 8];
                v4f pa0 = *(const v4f*)&ip[0];
                v4f pb0 = *(const v4f*)&ip[4];
                v4f pa1 = *(const v4f*)&ip[2080];   // vertex v0L+8
                v4f pb1 = *(const v4f*)&ip[2084];
                v2f x1_0 = pa0.zw, x1n_0 = {pa0.w, -pa0.z};
                v2f x2_0 = pb0.xy, x2n_0 = {pb0.y, -pb0.x};
                v2f x3_0 = pb0.zw, x3n_0 = {pb0.w, -pb0.z};
                v2f x1_1 = pa1.zw, x1n_1 = {pa1.w, -pa1.z};
                v2f x2_1 = pb1.xy, x2n_1 = {pb1.y, -pb1.x};
                v2f x3_1 = pb1.zw, x3n_1 = {pb1.w, -pb1.z};
                const float* wrow = &Wl[dl * 256];
                #pragma unroll
                for (int j = 0; j < 4; ++j) {
                    v4f q0 = *(const v4f*)&wrow[(tg + 8 * j) * 4];
                    v4f q1 = *(const v4f*)&wrow[(tg + 8 * j) * 4 + 128];
                    v2f w2v = {q0.z, q0.z}, w3v = {q0.w, q0.w};
                    v2f w4v = {q1.x, q1.x}, w5v = {q1.y, q1.y};
                    v2f w6v = {q1.z, q1.z}, w7v = {q1.w, q1.w};
                    // vv = 0
                    A0[0][j] = pkfma(pa0.xy, q0.xy, A0[0][j]);
                    A1[0][j] = pkfma(x1_0, w2v, A1[0][j]);
                    A1[0][j] = pkfma(x1n_0, w3v, A1[0][j]);
                    A2[0][j] = pkfma(x2_0, w4v, A2[0][j]);
                    A2[0][j] = pkfma(x2n_0, w5v, A2[0][j]);
                    A3[0][j] = pkfma(x3_0, w6v, A3[0][j]);
                    A3[0][j] = pkfma(x3n_0, w7v, A3[0][j]);
                    // vv = 1
                    A0[1][j] = pkfma(pa1.xy, q0.xy, A0[1][j]);
                    A1[1][j] = pkfma(x1_1, w2v, A1[1][j]);
                    A1[1][j] = pkfma(x1n_1, w3v, A1[1][j]);
                    A2[1][j] = pkfma(x2_1, w4v, A2[1][j]);
                    A2[1][j] = pkfma(x2n_1, w5v, A2[1][j]);
                    A3[1][j] = pkfma(x3_1, w6v, A3[1][j]);
                    A3[1][j] = pkfma(x3n_1, w7v, A3[1][j]);
                }
            }
        }
    }

    // ---- IDFT8 + bias per (vv, t) ----
    float bj[4];
    #pragma unroll
    for (int j = 0; j < 4; ++j) bj[j] = bias[tg + 8 * j];

    float outk[2][8][4];  // [vv][k][j]
    #pragma unroll
    for (int vv = 0; vv < 2; ++vv) {
        #pragma unroll
        for (int j = 0; j < 4; ++j) {
            float C0 = A0[vv][j].x, C4 = A0[vv][j].y;
            float R1 = A1[vv][j].x, I1 = A1[vv][j].y;
            float R2 = A2[vv][j].x, I2 = A2[vv][j].y;
            float R3 = A3[vv][j].x, I3 = A3[vv][j].y;
            float e = 0.125f * (C0 + C4), o = 0.125f * (C0 - C4);
            float p = 0.25f * (R1 + R3), q = 0.25f * R2, s = 0.25f * (I1 - I3);
            float a_ = 0.25f * RT2 * (R1 - R3);
            float b_ = 0.25f * RT2 * (I1 + I3);
            float c_ = 0.25f * I2;
            float bb = bj[j];
            outk[vv][0][j] = e + p + q + bb;
            outk[vv][1][j] = o + a_ - b_ - c_ + bb;
            outk[vv][2][j] = e - s - q + bb;
            outk[vv][3][j] = o - a_ - b_ + c_ + bb;
            outk[vv][4][j] = e - p + q + bb;
            outk[vv][5][j] = o - a_ + b_ - c_ + bb;
            outk[vv][6][j] = e + s - q + bb;
            outk[vv][7][j] = o + a_ + b_ + c_ + bb;
        }
    }

    // ---- norms: wave-local reduce over tg (lane bits 3..5) + select ----
    float sel[2][4];
    int vOutA[2]; vOutA[0] = v0; vOutA[1] = v1;
    #pragma unroll
    for (int vv = 0; vv < 2; ++vv) {
        float norms[8];
        #pragma unroll
        for (int k = 0; k < 8; ++k) {
            float nl = 0.f;
            #pragma unroll
            for (int j = 0; j < 4; ++j)
                nl = fmaf(outk[vv][k][j], outk[vv][k][j], nl);
            nl += __shfl_xor(nl, 8);
            nl += __shfl_xor(nl, 16);
            nl += __shfl_xor(nl, 32);
            norms[k] = nl;
        }
        float best = -1.f;
        int bk = 0;
        #pragma unroll
        for (int k = 0; k < 8; ++k) {
            float n = sqrtf(norms[k]);
            if (n > best) { best = n; bk = k; }
        }
        #pragma unroll
        for (int j = 0; j < 4; ++j) sel[vv][j] = 0.f;
        #pragma unroll
        for (int k = 0; k < 8; ++k) {
            if (k == bk) {
                #pragma unroll
                for (int j = 0; j < 4; ++j) sel[vv][j] = outk[vv][k][j];
            }
        }
        if (vOutA[vv] < N) {
            float* o = s_out + (size_t)vOutA[vv] * 32 + tg;
            o[0]  = sel[vv][0];
            o[8]  = sel[vv][1];
            o[16] = sel[vv][2];
            o[24] = sel[vv][3];
        }
    }

    // ---- fused BN stats: per-block partial sum/sumsq per column t ----
    float pa_[4], pb_[4];
    #pragma unroll
    for (int j = 0; j < 4; ++j) {
        float s0 = (v0 < N) ? sel[0][j] : 0.f;
        float s1 = (v1 < N) ? sel[1][j] : 0.f;
        pa_[j] = s0 + s1;
        pb_[j] = fmaf(s0, s0, s1 * s1);
    }
    #pragma unroll
    for (int j = 0; j < 4; ++j) {
        pa_[j] += __shfl_xor(pa_[j], 1);
        pb_[j] += __shfl_xor(pb_[j], 1);
        pa_[j] += __shfl_xor(pa_[j], 2);
        pb_[j] += __shfl_xor(pb_[j], 2);
        pa_[j] += __shfl_xor(pa_[j], 4);
        pb_[j] += __shfl_xor(pb_[j], 4);
    }
    __syncthreads();  // all waves done reading Wl -> reuse as stats scratch
    if (vg == 0) {
        float* wst = (float*)Wl;  // [wv][t][2]
        #pragma unroll
        for (int j = 0; j < 4; ++j) {
            int t = tg + 8 * j;
            wst[(wv * 32 + t) * 2 + 0] = pa_[j];
            wst[(wv * 32 + t) * 2 + 1] = pb_[j];
        }
    }
    __syncthreads();
    if (tid < 64) {
        const float* wst = (const float*)Wl;
        int t = tid >> 1, c = tid & 1;
        float s = wst[t * 2 + c] + wst[64 + t * 2 + c] +
                  wst[128 + t * 2 + c] + wst[192 + t * 2 + c];
        if (c == 0) atomicAdd(&sums[t], (double)s);
        else        atomicAdd(&sumsq[t], (double)s);
    }
}

// ---------------------------------------------------------------------------
// Finalize BN: scale = gamma * rsqrt(var + eps), shift = beta - mu*scale
// ---------------------------------------------------------------------------
__global__ void finalize_kernel(const double* __restrict__ sums,
                                const double* __restrict__ sumsq,
                                const float* __restrict__ gamma,
                                const float* __restrict__ beta,
                                float* __restrict__ scale,
                                float* __restrict__ shift, int n) {
    int t = threadIdx.x;
    if (t < 32) {
        double mu = sums[t] / (double)n;
        double var = sumsq[t] / (double)n - mu * mu;
        double sc = (double)gamma[t] / sqrt(var + 1e-3);
        scale[t] = (float)sc;
        shift[t] = (float)((double)beta[t] - mu * sc);
    }
}

// ---------------------------------------------------------------------------
// sig2 = relu(scale*s + shift)   (branch 1 epilogue -> conv2 input)
// ---------------------------------------------------------------------------
__global__ void affine_relu_kernel(const float* __restrict__ s,
                                   const float* __restrict__ scale,
                                   const float* __restrict__ shift,
                                   float* __restrict__ o, int n4) {
    int e = blockIdx.x * blockDim.x + threadIdx.x;
    if (e >= n4) return;
    int t0 = (e & 7) * 4;
    float4 x = ((const float4*)s)[e];
    float4 y;
    y.x = fmaxf(fmaf(scale[t0 + 0], x.x, shift[t0 + 0]), 0.f);
    y.y = fmaxf(fmaf(scale[t0 + 1], x.y, shift[t0 + 1]), 0.f);
    y.z = fmaxf(fmaf(scale[t0 + 2], x.z, shift[t0 + 2]), 0.f);
    y.w = fmaxf(fmaf(scale[t0 + 3], x.w, shift[t0 + 3]), 0.f);
    ((float4*)o)[e] = y;
}

// ---------------------------------------------------------------------------
// out = relu(scale*s + shift + signal)   (final residual epilogue)
// ---------------------------------------------------------------------------
__global__ void final_kernel(const float* __restrict__ s,
                             const float* __restrict__ scale,
                             const float* __restrict__ shift,
                             const float* __restrict__ sig,
                             float* __restrict__ o, int n4) {
    int e = blockIdx.x * blockDim.x + threadIdx.x;
    if (e >= n4) return;
    int t0 = (e & 7) * 4;
    float4 x = ((const float4*)s)[e];
    float4 z = ((const float4*)sig)[e];
    float4 y;
    y.x = fmaxf(fmaf(scale[t0 + 0], x.x, shift[t0 + 0]) + z.x, 0.f);
    y.y = fmaxf(fmaf(scale[t0 + 1], x.y, shift[t0 + 1]) + z.y, 0.f);
    y.z = fmaxf(fmaf(scale[t0 + 2], x.z, shift[t0 + 2]) + z.z, 0.f);
    y.w = fmaxf(fmaf(scale[t0 + 3], x.w, shift[t0 + 3]) + z.w, 0.f);
    ((float4*)o)[e] = y;
}

// ---------------------------------------------------------------------------
extern "C" void kernel_launch(void* const* d_in, const int* in_sizes, int n_in,
                              void* d_out, int out_size, void* d_ws, size_t ws_size,
                              hipStream_t stream) {
    const float* signal = (const float*)d_in[0];
    const int* bc_idx   = (const int*)d_in[1];
    const float* bc_w   = (const float*)d_in[2];
    const float* W1     = (const float*)d_in[3];
    const float* b1     = (const float*)d_in[4];
    const float* g1     = (const float*)d_in[5];
    const float* be1    = (const float*)d_in[6];
    const float* W2     = (const float*)d_in[7];
    const float* b2     = (const float*)d_in[8];
    const float* g2     = (const float*)d_in[9];
    const float* be2    = (const float*)d_in[10];
    float* out = (float*)d_out;

    const int N = in_sizes[0] / 32;  // 80000

    char* ws = (char*)d_ws;
    double* sums1  = (double*)ws;         // 32
    double* sumsq1 = sums1 + 32;
    double* sums2  = sums1 + 64;
    double* sumsq2 = sums1 + 96;
    float* scale1 = (float*)(ws + 1024);
    float* shift1 = scale1 + 32;
    float* scale2 = scale1 + 64;
    float* shift2 = scale1 + 96;
    float* Ws1 = (float*)(ws + 4096);                 // 40960 floats = 160 KB
    float* Ws2 = Ws1 + RR * DD * TT * 8;
    float* s1  = Ws2 + RR * DD * TT * 8;
    float* sg2 = s1 + (size_t)N * 32;
    float* s2  = sg2 + (size_t)N * 32;

    int nBlocks = (N + 63) / 64;               // 1250

    // zero stats + both W spectra in one launch
    prep_kernel<<<40, 256, 0, stream>>>(W1, W2, Ws1, Ws2, (double*)ws, (float*)(ws + 1024));

    // ---- branch 1: fused gather+DFT+spectral-conv+pool+stats ----
    fused_conv_kernel<<<nBlocks, 256, 0, stream>>>(signal, bc_idx, bc_w, Ws1, b1, s1,
                                                   sums1, sumsq1, N);
    finalize_kernel<<<1, 32, 0, stream>>>(sums1, sumsq1, g1, be1, scale1, shift1, N);
    affine_relu_kernel<<<(N * 8 + 255) / 256, 256, 0, stream>>>(s1, scale1, shift1, sg2, N * 8);

    // ---- branch 2 ----
    fused_conv_kernel<<<nBlocks, 256, 0, stream>>>(sg2, bc_idx, bc_w, Ws2, b2, s2,
                                                   sums2, sumsq2, N);
    finalize_kernel<<<1, 32, 0, stream>>>(sums2, sumsq2, g2, be2, scale2, shift2, N);

    // ---- residual + relu ----
    final_kernel<<<(N * 8 + 255) / 256, 256, 0, stream>>>(s2, scale2, shift2, signal, out, N * 8);
}